// Round 15
// baseline (343.751 us; speedup 1.0000x reference)
//
#include <hip/hip_runtime.h>
#include <hip/hip_fp16.h>
#include <hip/hip_cooperative_groups.h>
#include <float.h>

#define K_DIM 256
#define HW1 1024
#define NROWS 16384
#define NCODES 8192

namespace cg = cooperative_groups;

typedef __attribute__((ext_vector_type(8))) short bf16x8;
typedef __attribute__((ext_vector_type(4))) float f32x4;

__device__ __forceinline__ ushort bf16rn(float x) {
    unsigned u = __float_as_uint(x);
    return (ushort)((u + 0x7FFFu + ((u >> 16) & 1u)) >> 16);
}

__device__ __forceinline__ void gl16(const void* g, void* l) {
    __builtin_amdgcn_global_load_lds((const __attribute__((address_space(1))) void*)g,
                                     (__attribute__((address_space(3))) void*)l, 16, 0, 0);
}

// ---- kernel 1: FUSED  z-transpose/convert/znorm  +  emb->bf16  (r14) ----
__global__ __launch_bounds__(256) void k_cvt(const float* __restrict__ z,
                                             float* __restrict__ zf32,
                                             ushort* __restrict__ z16,
                                             float* __restrict__ zn,
                                             const float* __restrict__ emb,
                                             ushort* __restrict__ e16,
                                             unsigned* __restrict__ gcnt,
                                             float* __restrict__ loss) {
    __shared__ float ls[32 * 260];
    const int blk = blockIdx.x;
    const int t = threadIdx.x;
    if (blk >= 512) {
        const int eb = blk - 512;
        if (eb == 0) {
            gcnt[t] = 0u;
            if (t == 0) *loss = 0.f;
        }
#pragma unroll
        for (int i = 0; i < 8; ++i) {
            int f4 = eb * 2048 + i * 256 + t;
            float4 v = *(const float4*)(emb + (size_t)f4 * 4);
            ushort4 h;
            h.x = bf16rn(v.x); h.y = bf16rn(v.y);
            h.z = bf16rn(v.z); h.w = bf16rn(v.w);
            *(ushort4*)(e16 + (size_t)f4 * 4) = h;
        }
        return;
    }
    const int b = blk >> 5, hw0 = (blk & 31) * 32;
    const float* src = z + (size_t)b * 262144 + hw0;
#pragma unroll
    for (int i = 0; i < 2; ++i) {
        int m = t + i * 256;
        int kq = m >> 3, hq = m & 7;
        const float* s0 = src + (size_t)(kq * 4) * 1024 + hq * 4;
        float4 r0 = *(const float4*)(s0);
        float4 r1 = *(const float4*)(s0 + 1024);
        float4 r2 = *(const float4*)(s0 + 2048);
        float4 r3 = *(const float4*)(s0 + 3072);
        *(float4*)(ls + (hq * 4 + 0) * 260 + kq * 4) = make_float4(r0.x, r1.x, r2.x, r3.x);
        *(float4*)(ls + (hq * 4 + 1) * 260 + kq * 4) = make_float4(r0.y, r1.y, r2.y, r3.y);
        *(float4*)(ls + (hq * 4 + 2) * 260 + kq * 4) = make_float4(r0.z, r1.z, r2.z, r3.z);
        *(float4*)(ls + (hq * 4 + 3) * 260 + kq * 4) = make_float4(r0.w, r1.w, r2.w, r3.w);
    }
    __syncthreads();
    {
        const int w = t >> 6, cl = t & 63;
#pragma unroll
        for (int i = 0; i < 8; ++i) {
            int r = i * 4 + w;
            float4 v = *(const float4*)(ls + r * 260 + cl * 4);
            int n = b * 1024 + hw0 + r;
            *(float4*)(zf32 + (size_t)n * 256 + cl * 4) = v;
            ushort4 h;
            h.x = bf16rn(v.x); h.y = bf16rn(v.y);
            h.z = bf16rn(v.z); h.w = bf16rn(v.w);
            *(ushort4*)(z16 + (size_t)n * 256 + cl * 4) = h;
        }
    }
    if (t < 32) {
        const float* lr = ls + t * 260;
        float half[2];
#pragma unroll
        for (int h = 0; h < 2; ++h) {
            float rj[8];
            {
                float4 a = *(const float4*)(lr + h * 128);
                float4 b4 = *(const float4*)(lr + h * 128 + 4);
                float s;
                s = a.x * a.x; asm volatile("" : "+v"(s)); rj[0] = s;
                s = a.y * a.y; asm volatile("" : "+v"(s)); rj[1] = s;
                s = a.z * a.z; asm volatile("" : "+v"(s)); rj[2] = s;
                s = a.w * a.w; asm volatile("" : "+v"(s)); rj[3] = s;
                s = b4.x * b4.x; asm volatile("" : "+v"(s)); rj[4] = s;
                s = b4.y * b4.y; asm volatile("" : "+v"(s)); rj[5] = s;
                s = b4.z * b4.z; asm volatile("" : "+v"(s)); rj[6] = s;
                s = b4.w * b4.w; asm volatile("" : "+v"(s)); rj[7] = s;
            }
#pragma unroll
            for (int i = 1; i < 16; ++i) {
                float4 a = *(const float4*)(lr + h * 128 + 8 * i);
                float4 b4 = *(const float4*)(lr + h * 128 + 8 * i + 4);
                float s;
                s = a.x * a.x; asm volatile("" : "+v"(s)); rj[0] += s;
                s = a.y * a.y; asm volatile("" : "+v"(s)); rj[1] += s;
                s = a.z * a.z; asm volatile("" : "+v"(s)); rj[2] += s;
                s = a.w * a.w; asm volatile("" : "+v"(s)); rj[3] += s;
                s = b4.x * b4.x; asm volatile("" : "+v"(s)); rj[4] += s;
                s = b4.y * b4.y; asm volatile("" : "+v"(s)); rj[5] += s;
                s = b4.z * b4.z; asm volatile("" : "+v"(s)); rj[6] += s;
                s = b4.w * b4.w; asm volatile("" : "+v"(s)); rj[7] += s;
            }
            half[h] = ((rj[0] + rj[1]) + (rj[2] + rj[3])) +
                      ((rj[4] + rj[5]) + (rj[6] + rj[7]));
        }
        zn[b * 1024 + hw0 + t] = half[0] + half[1];
    }
}

// ---- kernel 2: bf16 MFMA coarse, 128x128, LDS transpose-reduce (r14) ----
__global__ __launch_bounds__(256) void k_coarse(
    const ushort* __restrict__ z16, const ushort* __restrict__ e16,
    ushort* __restrict__ tbl) {
    __shared__ char smem[35840];
    char* As = smem;
    char* Bs = smem + 16384;
    float* parts = (float*)smem;
    ushort* tb = (ushort*)(smem + 34816);
    const int tid = threadIdx.x;
    const int w = tid >> 6, lane = tid & 63;
    const int tx = lane & 15, q = lane >> 4;
    const int row0 = blockIdx.x * 128, c0 = blockIdx.y * 128;
    const int Am = (w & 1) * 64, Bn = (w >> 1) * 64;

    f32x4 acc[4][4];
#pragma unroll
    for (int mi = 0; mi < 4; ++mi)
#pragma unroll
        for (int ni = 0; ni < 4; ++ni) acc[mi][ni] = (f32x4){0.f, 0.f, 0.f, 0.f};

    for (int k0 = 0; k0 < K_DIM; k0 += 64) {
#pragma unroll
        for (int j = 0; j < 4; ++j) {
            int r = (w * 4 + j) * 8 + (lane >> 3);
            int c = (lane & 7) ^ (r & 7);
            gl16(z16 + (((size_t)(row0 + r)) << 8) + k0 + (c << 3),
                 As + (w * 4 + j) * 1024);
            gl16(e16 + (((size_t)(c0 + r)) << 8) + k0 + (c << 3),
                 Bs + (w * 4 + j) * 1024);
        }
        __syncthreads();
#pragma unroll
        for (int ks = 0; ks < 2; ++ks) {
            int cd = ks * 4;
            bf16x8 af[4], bfv[4];
#pragma unroll
            for (int mi = 0; mi < 4; ++mi)
                af[mi] = *(const bf16x8*)(As + (Am + mi * 16 + tx) * 128 +
                                          (((cd + q) ^ (tx & 7)) << 4));
#pragma unroll
            for (int ni = 0; ni < 4; ++ni)
                bfv[ni] = *(const bf16x8*)(Bs + (Bn + ni * 16 + tx) * 128 +
                                           (((cd + q) ^ (tx & 7)) << 4));
#pragma unroll
            for (int mi = 0; mi < 4; ++mi)
#pragma unroll
                for (int ni = 0; ni < 4; ++ni)
                    acc[mi][ni] = __builtin_amdgcn_mfma_f32_16x16x32_bf16(
                        af[mi], bfv[ni], acc[mi][ni], 0, 0, 0);
        }
        __syncthreads();
    }

#pragma unroll
    for (int g = 0; g < 2; ++g) {
        int gb = (w >> 1) * 2 + g;
#pragma unroll
        for (int mi = 0; mi < 4; ++mi) {
#pragma unroll
            for (int e = 0; e < 4; ++e) {
                float pm = fmaxf(acc[mi][2 * g][e], acc[mi][2 * g + 1][e]);
                int row = Am + mi * 16 + q * 4 + e;
                parts[(gb * 128 + row) * 17 + tx] = pm;
            }
        }
    }
    __syncthreads();
#pragma unroll
    for (int r2 = 0; r2 < 2; ++r2) {
        int p = tid * 2 + r2;
        const float* pr = parts + p * 17;
        float f0 = fmaxf(pr[0], pr[1]), f1 = fmaxf(pr[2], pr[3]);
        float f2 = fmaxf(pr[4], pr[5]), f3 = fmaxf(pr[6], pr[7]);
        float f4 = fmaxf(pr[8], pr[9]), f5 = fmaxf(pr[10], pr[11]);
        float f6 = fmaxf(pr[12], pr[13]), f7 = fmaxf(pr[14], pr[15]);
        float m = fmaxf(fmaxf(fmaxf(f0, f1), fmaxf(f2, f3)),
                        fmaxf(fmaxf(f4, f5), fmaxf(f6, f7)));
        tb[(p & 127) * 4 + (p >> 7)] = __half_as_ushort(__float2half(m));
    }
    __syncthreads();
    if (tid < 128) {
        ushort4 v = *(ushort4*)(tb + tid * 4);
        *(ushort4*)(tbl + (size_t)(row0 + tid) * 256 + blockIdx.y * 4) = v;
    }
}

// ---- kernel 3 (cooperative): flag -> grid.sync -> rescore -> grid.sync -> gather
// Grid 512 x 256 (2 blocks/CU at 41 KB LDS: co-residency safe). Each phase's
// math is byte-identical to the round-14 kernels; only block->work maps change
// (atomicMin / max are order-independent).
__global__ __launch_bounds__(256) void k_tail(
    const float* __restrict__ zf32, const float* __restrict__ emb,
    const float* __restrict__ zn, const ushort* __restrict__ tbl,
    ushort* __restrict__ bucket, unsigned* __restrict__ gcnt,
    unsigned long long* __restrict__ best, const float* __restrict__ z,
    float* __restrict__ zq, float* __restrict__ oidx, float* __restrict__ loss) {
    __shared__ float eg[32 * 257];   // B: code tile | C: 16x257 gather tile
    __shared__ float zs[8][256];
    __shared__ ushort rid[8];
    __shared__ float arow[8];
    __shared__ float lsum[4];
    cg::grid_group grid = cg::this_grid();
    const int blk = blockIdx.x;
    const int t = threadIdx.x;
    const int wid = t >> 6, lane = t & 63;

    // ---------- phase A: flag (8 units of 4 rows per block) ----------
    for (int u = blk; u < 4096; u += 512) {
        const int n = u * 4 + wid;
        if (lane == 0) best[n] = 0xFFFFFFFFFFFFFFFFull;
        ushort4 raw = *(const ushort4*)(tbl + (size_t)n * 256 + lane * 4);
        float gm[4];
        gm[0] = __half2float(__ushort_as_half(raw.x));
        gm[1] = __half2float(__ushort_as_half(raw.y));
        gm[2] = __half2float(__ushort_as_half(raw.z));
        gm[3] = __half2float(__ushort_as_half(raw.w));
        float gmax = fmaxf(fmaxf(gm[0], gm[1]), fmaxf(gm[2], gm[3]));
#pragma unroll
        for (int m = 1; m < 64; m <<= 1) gmax = fmaxf(gmax, __shfl_xor(gmax, m, 64));
        const float th = gmax - 1.0e-4f;
#pragma unroll
        for (int i = 0; i < 4; ++i) {
            if (gm[i] >= th) {
                int g = lane * 4 + i;
                unsigned pos = atomicAdd(&gcnt[g], 1u);
                bucket[(size_t)g * NROWS + pos] = (ushort)n;
            }
        }
    }
    grid.sync();

    // ---------- phase B: exact rescore (2 splits per group) ----------
    {
        const int g = blk & 255;
        const int split = blk >> 8;  // 0 or 1
        const int cnt = (int)gcnt[g];
        if (split * 8 < cnt) {
#pragma unroll
            for (int i = 0; i < 8; ++i) {
                int f = t + i * 256;
                int c = f >> 6, k4 = f & 63;
                float4 v = *(const float4*)(emb + (size_t)(g * 32 + c) * 256 + k4 * 4);
                float* dst = eg + c * 257 + k4 * 4;
                dst[0] = v.x; dst[1] = v.y; dst[2] = v.z; dst[3] = v.w;
            }
            for (int base = split * 8; base < cnt; base += 16) {
                __syncthreads();
                if (t < 8) {
                    int i = base + t;
                    if (i < cnt) {
                        ushort r = bucket[(size_t)g * NROWS + i];
                        rid[t] = r;
                        arow[t] = zn[r];
                    } else {
                        rid[t] = 0xFFFF;
                    }
                }
                __syncthreads();
#pragma unroll
                for (int i = 0; i < 2; ++i) {
                    int f = t + i * 256;
                    int s = f >> 6, k4 = f & 63;
                    if (rid[s] != 0xFFFF)
                        *(float4*)(&zs[s][k4 * 4]) =
                            *(const float4*)(zf32 + (size_t)rid[s] * 256 + k4 * 4);
                }
                __syncthreads();
                const int slot = wid * 2 + (lane >> 5);
                const int code = lane & 31;
                if (rid[slot] != 0xFFFF) {
                    const float* zr = zs[slot];
                    const float* er = eg + code * 257;
                    float acc = 0.f;
#pragma unroll 8
                    for (int k = 0; k < 256; ++k) acc = fmaf(zr[k], er[k], acc);
                    float d = arow[slot] - 2.f * acc;
                    unsigned fb = __float_as_uint(d);
                    fb ^= (fb & 0x80000000u) ? 0xFFFFFFFFu : 0x80000000u;
                    unsigned long long pk =
                        ((unsigned long long)fb << 32) | (unsigned)(g * 32 + code);
#pragma unroll
                    for (int m = 1; m < 32; m <<= 1) {
                        unsigned long long o = __shfl_xor(pk, m, 64);
                        if (o < pk) pk = o;
                    }
                    if ((lane & 31) == 0) atomicMin(&best[rid[slot]], pk);
                }
            }
        }
    }
    grid.sync();

    // ---------- phase C: gather (2 tiles of 16 rows per block) ----------
    for (int tile = blk; tile < 1024; tile += 512) {
        const int n0 = tile * 16;
        const int b = n0 >> 10, hw0 = n0 & 1023;
        {
            const int row = t >> 4, p = t & 15;
            const int code = (int)(unsigned)(best[n0 + row] & 0xFFFFFFFFull);
            if (p == 0) oidx[n0 + row] = (float)code;
            const float* er = emb + (size_t)code * 256 + p * 16;
            float* dst = eg + row * 257 + p * 16;
#pragma unroll
            for (int i = 0; i < 4; ++i)
                *(float4*)(dst + i * 4) = *(const float4*)(er + i * 4);
        }
        __syncthreads();
        const int csub = lane >> 2, hwq = lane & 3;
        float acc = 0.f;
        const size_t zb = (size_t)b * 262144 + hw0 + hwq * 4;
#pragma unroll
        for (int it = 0; it < 4; ++it) {
            int c = wid * 64 + it * 16 + csub;
            size_t off = zb + (size_t)c * 1024;
            float4 zv = *(const float4*)(z + off);
            int r = hwq * 4;
            float4 ev = make_float4(eg[(r + 0) * 257 + c], eg[(r + 1) * 257 + c],
                                    eg[(r + 2) * 257 + c], eg[(r + 3) * 257 + c]);
            *(float4*)(zq + off) = ev;
            float d0 = ev.x - zv.x, d1 = ev.y - zv.y;
            float d2 = ev.z - zv.z, d3 = ev.w - zv.w;
            acc += d0 * d0 + d1 * d1 + d2 * d2 + d3 * d3;
        }
#pragma unroll
        for (int m = 32; m; m >>= 1) acc += __shfl_xor(acc, m, 64);
        if (lane == 0) lsum[wid] = acc;
        __syncthreads();
        if (t == 0) {
            float s = (lsum[0] + lsum[1]) + (lsum[2] + lsum[3]);
            atomicAdd(loss, s * (2.f / 4194304.f));
        }
        __syncthreads();  // protect eg/lsum reuse next tile
    }
}

extern "C" void kernel_launch(void* const* d_in, const int* in_sizes, int n_in,
                              void* d_out, int out_size, void* d_ws, size_t ws_size,
                              hipStream_t stream) {
    const float* z = (const float*)d_in[0];
    const float* emb = (const float*)d_in[1];
    float* out = (float*)d_out;
    float* zq = out;
    float* loss = out + 4194304;
    float* oidx = out + 4194305;
    float* zf32 = out;

    ushort* z16 = (ushort*)d_ws;               // 8 MB; dead after k_coarse
    ushort* e16 = z16 + 4194304;               // 4 MB
    ushort* tbl = e16 + 2097152;               // 8 MB [n][256] f16
    float* zn = (float*)(tbl + 4194304);       // 64 KB
    unsigned long long* best = (unsigned long long*)(zn + 16384);  // 128 KB
    unsigned* gcnt = (unsigned*)(best + 16384);                    // 1 KB
    ushort* bucket = z16;                      // alias dead z16

    k_cvt<<<dim3(768), dim3(256), 0, stream>>>(z, zf32, z16, zn, emb, e16, gcnt, loss);
    k_coarse<<<dim3(NROWS / 128, NCODES / 128), dim3(256), 0, stream>>>(z16, e16, tbl);
    void* args[] = {(void*)&zf32, (void*)&emb, (void*)&zn,  (void*)&tbl,
                    (void*)&bucket, (void*)&gcnt, (void*)&best, (void*)&z,
                    (void*)&zq, (void*)&oidx, (void*)&loss};
    hipLaunchCooperativeKernel((const void*)k_tail, dim3(512), dim3(256), args, 0, stream);
}

// Round 16
// 309.330 us; speedup vs baseline: 1.1113x; 1.1113x over previous
//
#include <hip/hip_runtime.h>
#include <hip/hip_fp16.h>
#include <float.h>

#define K_DIM 256
#define HW1 1024
#define NROWS 16384
#define NCODES 8192

typedef __attribute__((ext_vector_type(8))) short bf16x8;
typedef __attribute__((ext_vector_type(4))) float f32x4;

__device__ __forceinline__ ushort bf16rn(float x) {
    unsigned u = __float_as_uint(x);
    return (ushort)((u + 0x7FFFu + ((u >> 16) & 1u)) >> 16);
}

__device__ __forceinline__ void gl16(const void* g, void* l) {
    __builtin_amdgcn_global_load_lds((const __attribute__((address_space(1))) void*)g,
                                     (__attribute__((address_space(3))) void*)l, 16, 0, 0);
}

// ---- kernel 1: FUSED  z-transpose/convert/znorm  +  emb->bf16  (r14) ----
__global__ __launch_bounds__(256) void k_cvt(const float* __restrict__ z,
                                             float* __restrict__ zf32,
                                             ushort* __restrict__ z16,
                                             float* __restrict__ zn,
                                             const float* __restrict__ emb,
                                             ushort* __restrict__ e16,
                                             unsigned* __restrict__ gcnt,
                                             float* __restrict__ loss) {
    __shared__ float ls[32 * 260];
    const int blk = blockIdx.x;
    const int t = threadIdx.x;
    if (blk >= 512) {
        const int eb = blk - 512;
        if (eb == 0) {
            gcnt[t] = 0u;
            if (t == 0) *loss = 0.f;
        }
#pragma unroll
        for (int i = 0; i < 8; ++i) {
            int f4 = eb * 2048 + i * 256 + t;
            float4 v = *(const float4*)(emb + (size_t)f4 * 4);
            ushort4 h;
            h.x = bf16rn(v.x); h.y = bf16rn(v.y);
            h.z = bf16rn(v.z); h.w = bf16rn(v.w);
            *(ushort4*)(e16 + (size_t)f4 * 4) = h;
        }
        return;
    }
    const int b = blk >> 5, hw0 = (blk & 31) * 32;
    const float* src = z + (size_t)b * 262144 + hw0;
#pragma unroll
    for (int i = 0; i < 2; ++i) {
        int m = t + i * 256;
        int kq = m >> 3, hq = m & 7;
        const float* s0 = src + (size_t)(kq * 4) * 1024 + hq * 4;
        float4 r0 = *(const float4*)(s0);
        float4 r1 = *(const float4*)(s0 + 1024);
        float4 r2 = *(const float4*)(s0 + 2048);
        float4 r3 = *(const float4*)(s0 + 3072);
        *(float4*)(ls + (hq * 4 + 0) * 260 + kq * 4) = make_float4(r0.x, r1.x, r2.x, r3.x);
        *(float4*)(ls + (hq * 4 + 1) * 260 + kq * 4) = make_float4(r0.y, r1.y, r2.y, r3.y);
        *(float4*)(ls + (hq * 4 + 2) * 260 + kq * 4) = make_float4(r0.z, r1.z, r2.z, r3.z);
        *(float4*)(ls + (hq * 4 + 3) * 260 + kq * 4) = make_float4(r0.w, r1.w, r2.w, r3.w);
    }
    __syncthreads();
    {
        const int w = t >> 6, cl = t & 63;
#pragma unroll
        for (int i = 0; i < 8; ++i) {
            int r = i * 4 + w;
            float4 v = *(const float4*)(ls + r * 260 + cl * 4);
            int n = b * 1024 + hw0 + r;
            *(float4*)(zf32 + (size_t)n * 256 + cl * 4) = v;
            ushort4 h;
            h.x = bf16rn(v.x); h.y = bf16rn(v.y);
            h.z = bf16rn(v.z); h.w = bf16rn(v.w);
            *(ushort4*)(z16 + (size_t)n * 256 + cl * 4) = h;
        }
    }
    if (t < 32) {
        const float* lr = ls + t * 260;
        float half[2];
#pragma unroll
        for (int h = 0; h < 2; ++h) {
            float rj[8];
            {
                float4 a = *(const float4*)(lr + h * 128);
                float4 b4 = *(const float4*)(lr + h * 128 + 4);
                float s;
                s = a.x * a.x; asm volatile("" : "+v"(s)); rj[0] = s;
                s = a.y * a.y; asm volatile("" : "+v"(s)); rj[1] = s;
                s = a.z * a.z; asm volatile("" : "+v"(s)); rj[2] = s;
                s = a.w * a.w; asm volatile("" : "+v"(s)); rj[3] = s;
                s = b4.x * b4.x; asm volatile("" : "+v"(s)); rj[4] = s;
                s = b4.y * b4.y; asm volatile("" : "+v"(s)); rj[5] = s;
                s = b4.z * b4.z; asm volatile("" : "+v"(s)); rj[6] = s;
                s = b4.w * b4.w; asm volatile("" : "+v"(s)); rj[7] = s;
            }
#pragma unroll
            for (int i = 1; i < 16; ++i) {
                float4 a = *(const float4*)(lr + h * 128 + 8 * i);
                float4 b4 = *(const float4*)(lr + h * 128 + 8 * i + 4);
                float s;
                s = a.x * a.x; asm volatile("" : "+v"(s)); rj[0] += s;
                s = a.y * a.y; asm volatile("" : "+v"(s)); rj[1] += s;
                s = a.z * a.z; asm volatile("" : "+v"(s)); rj[2] += s;
                s = a.w * a.w; asm volatile("" : "+v"(s)); rj[3] += s;
                s = b4.x * b4.x; asm volatile("" : "+v"(s)); rj[4] += s;
                s = b4.y * b4.y; asm volatile("" : "+v"(s)); rj[5] += s;
                s = b4.z * b4.z; asm volatile("" : "+v"(s)); rj[6] += s;
                s = b4.w * b4.w; asm volatile("" : "+v"(s)); rj[7] += s;
            }
            half[h] = ((rj[0] + rj[1]) + (rj[2] + rj[3])) +
                      ((rj[4] + rj[5]) + (rj[6] + rj[7]));
        }
        zn[b * 1024 + hw0 + t] = half[0] + half[1];
    }
}

// ---- kernel 2: bf16 MFMA coarse, tile 128x256, wave-tile 64x128,
// LDS transpose-reduce epilogue in two row-halves (parts fits 48 KB arena).
// ds_read/MFMA = 0.375 -> MFMA-bound inner loop; half the blocks/barriers. ----
__global__ __launch_bounds__(256) void k_coarse(
    const ushort* __restrict__ z16, const ushort* __restrict__ e16,
    ushort* __restrict__ tbl) {
    __shared__ char smem[49152];
    char* As = smem;                       // [128][64] bf16, 16 KB
    char* Bs = smem + 16384;               // [256][64] bf16, 32 KB
    float* parts = (float*)smem;           // epilogue overlay: 512*17 f32 = 34816 B
    ushort* tb = (ushort*)(smem + 34816);  // 128*8 ushort = 2 KB
    const int tid = threadIdx.x;
    const int w = tid >> 6, lane = tid & 63;
    const int tx = lane & 15, q = lane >> 4;
    const int row0 = blockIdx.x * 128, c0 = blockIdx.y * 256;
    const int Am = (w & 1) * 64, Bn = (w >> 1) * 128;

    f32x4 acc[4][8];
#pragma unroll
    for (int mi = 0; mi < 4; ++mi)
#pragma unroll
        for (int ni = 0; ni < 8; ++ni) acc[mi][ni] = (f32x4){0.f, 0.f, 0.f, 0.f};

    for (int k0 = 0; k0 < K_DIM; k0 += 64) {
#pragma unroll
        for (int j = 0; j < 4; ++j) {  // A: 128 rows
            int r = (w * 4 + j) * 8 + (lane >> 3);
            int c = (lane & 7) ^ (r & 7);
            gl16(z16 + (((size_t)(row0 + r)) << 8) + k0 + (c << 3),
                 As + (w * 4 + j) * 1024);
        }
#pragma unroll
        for (int j = 0; j < 8; ++j) {  // B: 256 rows
            int r = (w * 8 + j) * 8 + (lane >> 3);
            int c = (lane & 7) ^ (r & 7);
            gl16(e16 + (((size_t)(c0 + r)) << 8) + k0 + (c << 3),
                 Bs + (w * 8 + j) * 1024);
        }
        __syncthreads();
#pragma unroll
        for (int ks = 0; ks < 2; ++ks) {
            int cd = ks * 4;
            bf16x8 af[4], bfv[8];
#pragma unroll
            for (int mi = 0; mi < 4; ++mi)
                af[mi] = *(const bf16x8*)(As + (Am + mi * 16 + tx) * 128 +
                                          (((cd + q) ^ (tx & 7)) << 4));
#pragma unroll
            for (int ni = 0; ni < 8; ++ni)
                bfv[ni] = *(const bf16x8*)(Bs + (Bn + ni * 16 + tx) * 128 +
                                           (((cd + q) ^ (tx & 7)) << 4));
#pragma unroll
            for (int mi = 0; mi < 4; ++mi)
#pragma unroll
                for (int ni = 0; ni < 8; ++ni)
                    acc[mi][ni] = __builtin_amdgcn_mfma_f32_16x16x32_bf16(
                        af[mi], bfv[ni], acc[mi][ni], 0, 0, 0);
        }
        __syncthreads();  // final instance also protects parts overlay
    }

    // epilogue: two row-halves; within each, scatter partials then reduce 16.
#pragma unroll
    for (int rh = 0; rh < 2; ++rh) {
        if ((w & 1) == rh) {  // wave-uniform: waves owning rows rh*64..+63
#pragma unroll
            for (int g = 0; g < 4; ++g) {
                int gb = (w >> 1) * 4 + g;  // block-local group 0..7
#pragma unroll
                for (int mi = 0; mi < 4; ++mi) {
#pragma unroll
                    for (int e = 0; e < 4; ++e) {
                        float pm = fmaxf(acc[mi][2 * g][e], acc[mi][2 * g + 1][e]);
                        int rl = mi * 16 + q * 4 + e;  // 0..63 within half
                        parts[(gb * 64 + rl) * 17 + tx] = pm;
                    }
                }
            }
        }
        __syncthreads();
#pragma unroll
        for (int r2 = 0; r2 < 2; ++r2) {
            int p = tid * 2 + r2;  // 0..511 = gb*64 + rl
            const float* pr = parts + p * 17;
            float f0 = fmaxf(pr[0], pr[1]), f1 = fmaxf(pr[2], pr[3]);
            float f2 = fmaxf(pr[4], pr[5]), f3 = fmaxf(pr[6], pr[7]);
            float f4 = fmaxf(pr[8], pr[9]), f5 = fmaxf(pr[10], pr[11]);
            float f6 = fmaxf(pr[12], pr[13]), f7 = fmaxf(pr[14], pr[15]);
            float m = fmaxf(fmaxf(fmaxf(f0, f1), fmaxf(f2, f3)),
                            fmaxf(fmaxf(f4, f5), fmaxf(f6, f7)));
            int row = rh * 64 + (p & 63);
            tb[row * 8 + (p >> 6)] = __half_as_ushort(__float2half(m));
        }
        __syncthreads();
    }
    if (tid < 128) {
        ushort4 v0 = *(ushort4*)(tb + tid * 8);
        ushort4 v1 = *(ushort4*)(tb + tid * 8 + 4);
        ushort* dst = tbl + (size_t)(row0 + tid) * 256 + blockIdx.y * 8;
        *(ushort4*)(dst) = v0;
        *(ushort4*)(dst + 4) = v1;
    }
}

// ---- kernel 3: flag pass (r14) ----
__global__ void k_flag(const ushort* __restrict__ tbl, ushort* __restrict__ bucket,
                       unsigned* __restrict__ gcnt,
                       unsigned long long* __restrict__ best) {
    const int wid = threadIdx.x >> 6, lane = threadIdx.x & 63;
    const int n = blockIdx.x * 4 + wid;
    if (lane == 0) best[n] = 0xFFFFFFFFFFFFFFFFull;
    ushort4 raw = *(const ushort4*)(tbl + (size_t)n * 256 + lane * 4);
    float gm[4];
    gm[0] = __half2float(__ushort_as_half(raw.x));
    gm[1] = __half2float(__ushort_as_half(raw.y));
    gm[2] = __half2float(__ushort_as_half(raw.z));
    gm[3] = __half2float(__ushort_as_half(raw.w));
    float gmax = fmaxf(fmaxf(gm[0], gm[1]), fmaxf(gm[2], gm[3]));
#pragma unroll
    for (int m = 1; m < 64; m <<= 1) gmax = fmaxf(gmax, __shfl_xor(gmax, m, 64));
    const float th = gmax - 1.0e-4f;
#pragma unroll
    for (int i = 0; i < 4; ++i) {
        if (gm[i] >= th) {
            int g = lane * 4 + i;
            unsigned pos = atomicAdd(&gcnt[g], 1u);
            bucket[(size_t)g * NROWS + pos] = (ushort)n;
        }
    }
}

// ---- kernel 4: exact rescore; 4 blocks per group (r14) ----
__global__ __launch_bounds__(256) void k_rescore2(
    const float* __restrict__ zf32, const float* __restrict__ emb,
    const float* __restrict__ zn, const ushort* __restrict__ bucket,
    const unsigned* __restrict__ gcnt, unsigned long long* __restrict__ best) {
    __shared__ float eg[32 * 257];
    __shared__ float zs[8][256];
    __shared__ ushort rid[8];
    __shared__ float arow[8];
    const int g = blockIdx.x >> 2;
    const int split = blockIdx.x & 3;
    const int t = threadIdx.x;
    const int cnt = (int)gcnt[g];
    if (split * 8 >= cnt) return;
#pragma unroll
    for (int i = 0; i < 8; ++i) {
        int f = t + i * 256;
        int c = f >> 6, k4 = f & 63;
        float4 v = *(const float4*)(emb + (size_t)(g * 32 + c) * 256 + k4 * 4);
        float* dst = eg + c * 257 + k4 * 4;
        dst[0] = v.x; dst[1] = v.y; dst[2] = v.z; dst[3] = v.w;
    }
    for (int base = split * 8; base < cnt; base += 32) {
        __syncthreads();
        if (t < 8) {
            int i = base + t;
            if (i < cnt) {
                ushort r = bucket[(size_t)g * NROWS + i];
                rid[t] = r;
                arow[t] = zn[r];
            } else {
                rid[t] = 0xFFFF;
            }
        }
        __syncthreads();
#pragma unroll
        for (int i = 0; i < 2; ++i) {
            int f = t + i * 256;
            int s = f >> 6, k4 = f & 63;
            if (rid[s] != 0xFFFF)
                *(float4*)(&zs[s][k4 * 4]) =
                    *(const float4*)(zf32 + (size_t)rid[s] * 256 + k4 * 4);
        }
        __syncthreads();
        const int lane = t & 63, w = t >> 6;
        const int slot = w * 2 + (lane >> 5);
        const int code = lane & 31;
        if (rid[slot] != 0xFFFF) {
            const float* zr = zs[slot];
            const float* er = eg + code * 257;
            float acc = 0.f;
#pragma unroll 8
            for (int k = 0; k < 256; ++k) acc = fmaf(zr[k], er[k], acc);
            float d = arow[slot] - 2.f * acc;
            unsigned fb = __float_as_uint(d);
            fb ^= (fb & 0x80000000u) ? 0xFFFFFFFFu : 0x80000000u;
            unsigned long long pk =
                ((unsigned long long)fb << 32) | (unsigned)(g * 32 + code);
#pragma unroll
            for (int m = 1; m < 32; m <<= 1) {
                unsigned long long o = __shfl_xor(pk, m, 64);
                if (o < pk) pk = o;
            }
            if ((lane & 31) == 0) atomicMin(&best[rid[slot]], pk);
        }
    }
}

// ---- kernel 5: gather z_q + loss + oidx; 16 rows/block, pitch-257 (r14) ----
__global__ __launch_bounds__(256) void k_gather(
    const float* __restrict__ z, const float* __restrict__ emb,
    const unsigned long long* __restrict__ best, float* __restrict__ zq,
    float* __restrict__ oidx, float* __restrict__ loss) {
    __shared__ float eg[16 * 257];
    __shared__ float lsum[4];
    const int t = threadIdx.x;
    const int n0 = blockIdx.x * 16;
    const int b = n0 >> 10, hw0 = n0 & 1023;
    {
        const int row = t >> 4, p = t & 15;
        const int code = (int)(unsigned)(best[n0 + row] & 0xFFFFFFFFull);
        if (p == 0) oidx[n0 + row] = (float)code;
        const float* er = emb + (size_t)code * 256 + p * 16;
        float* dst = eg + row * 257 + p * 16;
#pragma unroll
        for (int i = 0; i < 4; ++i)
            *(float4*)(dst + i * 4) = *(const float4*)(er + i * 4);
    }
    __syncthreads();
    const int w = t >> 6, lane = t & 63;
    const int csub = lane >> 2, hwq = lane & 3;
    float acc = 0.f;
    const size_t zb = (size_t)b * 262144 + hw0 + hwq * 4;
#pragma unroll
    for (int it = 0; it < 4; ++it) {
        int c = w * 64 + it * 16 + csub;
        size_t off = zb + (size_t)c * 1024;
        float4 zv = *(const float4*)(z + off);
        int r = hwq * 4;
        float4 ev = make_float4(eg[(r + 0) * 257 + c], eg[(r + 1) * 257 + c],
                                eg[(r + 2) * 257 + c], eg[(r + 3) * 257 + c]);
        *(float4*)(zq + off) = ev;
        float d0 = ev.x - zv.x, d1 = ev.y - zv.y;
        float d2 = ev.z - zv.z, d3 = ev.w - zv.w;
        acc += d0 * d0 + d1 * d1 + d2 * d2 + d3 * d3;
    }
#pragma unroll
    for (int m = 32; m; m >>= 1) acc += __shfl_xor(acc, m, 64);
    if (lane == 0) lsum[w] = acc;
    __syncthreads();
    if (t == 0) {
        float s = (lsum[0] + lsum[1]) + (lsum[2] + lsum[3]);
        atomicAdd(loss, s * (2.f / 4194304.f));
    }
}

extern "C" void kernel_launch(void* const* d_in, const int* in_sizes, int n_in,
                              void* d_out, int out_size, void* d_ws, size_t ws_size,
                              hipStream_t stream) {
    const float* z = (const float*)d_in[0];
    const float* emb = (const float*)d_in[1];
    float* out = (float*)d_out;
    float* zq = out;
    float* loss = out + 4194304;
    float* oidx = out + 4194305;
    float* zf32 = out;

    ushort* z16 = (ushort*)d_ws;               // 8 MB; dead after k_coarse
    ushort* e16 = z16 + 4194304;               // 4 MB
    ushort* tbl = e16 + 2097152;               // 8 MB [n][256] f16
    float* zn = (float*)(tbl + 4194304);       // 64 KB
    unsigned long long* best = (unsigned long long*)(zn + 16384);  // 128 KB
    unsigned* gcnt = (unsigned*)(best + 16384);                    // 1 KB
    ushort* bucket = z16;                      // alias dead z16

    k_cvt<<<dim3(768), dim3(256), 0, stream>>>(z, zf32, z16, zn, emb, e16, gcnt, loss);
    k_coarse<<<dim3(NROWS / 128, NCODES / 256), dim3(256), 0, stream>>>(z16, e16, tbl);
    k_flag<<<dim3(NROWS / 4), dim3(256), 0, stream>>>(tbl, bucket, gcnt, best);
    k_rescore2<<<dim3(1024), dim3(256), 0, stream>>>(zf32, emb, zn, bucket, gcnt, best);
    k_gather<<<dim3(NROWS / 16), dim3(256), 0, stream>>>(z, emb, best, zq, oidx, loss);
}

// Round 17
// 232.487 us; speedup vs baseline: 1.4786x; 1.3305x over previous
//
#include <hip/hip_runtime.h>
#include <hip/hip_fp16.h>
#include <float.h>

#define K_DIM 256
#define HW1 1024
#define NROWS 16384
#define NCODES 8192

typedef __attribute__((ext_vector_type(8))) short bf16x8;
typedef __attribute__((ext_vector_type(4))) float f32x4;

__device__ __forceinline__ ushort bf16rn(float x) {
    unsigned u = __float_as_uint(x);
    return (ushort)((u + 0x7FFFu + ((u >> 16) & 1u)) >> 16);
}

__device__ __forceinline__ void gl16(const void* g, void* l) {
    __builtin_amdgcn_global_load_lds((const __attribute__((address_space(1))) void*)g,
                                     (__attribute__((address_space(3))) void*)l, 16, 0, 0);
}

// ---- kernel 1: FUSED  z-transpose/convert/znorm  +  emb->bf16  (r14) ----
__global__ __launch_bounds__(256) void k_cvt(const float* __restrict__ z,
                                             float* __restrict__ zf32,
                                             ushort* __restrict__ z16,
                                             float* __restrict__ zn,
                                             const float* __restrict__ emb,
                                             ushort* __restrict__ e16,
                                             unsigned* __restrict__ gcnt,
                                             float* __restrict__ loss) {
    __shared__ float ls[32 * 260];
    const int blk = blockIdx.x;
    const int t = threadIdx.x;
    if (blk >= 512) {
        const int eb = blk - 512;
        if (eb == 0) {
            gcnt[t] = 0u;
            if (t == 0) *loss = 0.f;
        }
#pragma unroll
        for (int i = 0; i < 8; ++i) {
            int f4 = eb * 2048 + i * 256 + t;
            float4 v = *(const float4*)(emb + (size_t)f4 * 4);
            ushort4 h;
            h.x = bf16rn(v.x); h.y = bf16rn(v.y);
            h.z = bf16rn(v.z); h.w = bf16rn(v.w);
            *(ushort4*)(e16 + (size_t)f4 * 4) = h;
        }
        return;
    }
    const int b = blk >> 5, hw0 = (blk & 31) * 32;
    const float* src = z + (size_t)b * 262144 + hw0;
#pragma unroll
    for (int i = 0; i < 2; ++i) {
        int m = t + i * 256;
        int kq = m >> 3, hq = m & 7;
        const float* s0 = src + (size_t)(kq * 4) * 1024 + hq * 4;
        float4 r0 = *(const float4*)(s0);
        float4 r1 = *(const float4*)(s0 + 1024);
        float4 r2 = *(const float4*)(s0 + 2048);
        float4 r3 = *(const float4*)(s0 + 3072);
        *(float4*)(ls + (hq * 4 + 0) * 260 + kq * 4) = make_float4(r0.x, r1.x, r2.x, r3.x);
        *(float4*)(ls + (hq * 4 + 1) * 260 + kq * 4) = make_float4(r0.y, r1.y, r2.y, r3.y);
        *(float4*)(ls + (hq * 4 + 2) * 260 + kq * 4) = make_float4(r0.z, r1.z, r2.z, r3.z);
        *(float4*)(ls + (hq * 4 + 3) * 260 + kq * 4) = make_float4(r0.w, r1.w, r2.w, r3.w);
    }
    __syncthreads();
    {
        const int w = t >> 6, cl = t & 63;
#pragma unroll
        for (int i = 0; i < 8; ++i) {
            int r = i * 4 + w;
            float4 v = *(const float4*)(ls + r * 260 + cl * 4);
            int n = b * 1024 + hw0 + r;
            *(float4*)(zf32 + (size_t)n * 256 + cl * 4) = v;
            ushort4 h;
            h.x = bf16rn(v.x); h.y = bf16rn(v.y);
            h.z = bf16rn(v.z); h.w = bf16rn(v.w);
            *(ushort4*)(z16 + (size_t)n * 256 + cl * 4) = h;
        }
    }
    if (t < 32) {
        const float* lr = ls + t * 260;
        float half[2];
#pragma unroll
        for (int h = 0; h < 2; ++h) {
            float rj[8];
            {
                float4 a = *(const float4*)(lr + h * 128);
                float4 b4 = *(const float4*)(lr + h * 128 + 4);
                float s;
                s = a.x * a.x; asm volatile("" : "+v"(s)); rj[0] = s;
                s = a.y * a.y; asm volatile("" : "+v"(s)); rj[1] = s;
                s = a.z * a.z; asm volatile("" : "+v"(s)); rj[2] = s;
                s = a.w * a.w; asm volatile("" : "+v"(s)); rj[3] = s;
                s = b4.x * b4.x; asm volatile("" : "+v"(s)); rj[4] = s;
                s = b4.y * b4.y; asm volatile("" : "+v"(s)); rj[5] = s;
                s = b4.z * b4.z; asm volatile("" : "+v"(s)); rj[6] = s;
                s = b4.w * b4.w; asm volatile("" : "+v"(s)); rj[7] = s;
            }
#pragma unroll
            for (int i = 1; i < 16; ++i) {
                float4 a = *(const float4*)(lr + h * 128 + 8 * i);
                float4 b4 = *(const float4*)(lr + h * 128 + 8 * i + 4);
                float s;
                s = a.x * a.x; asm volatile("" : "+v"(s)); rj[0] += s;
                s = a.y * a.y; asm volatile("" : "+v"(s)); rj[1] += s;
                s = a.z * a.z; asm volatile("" : "+v"(s)); rj[2] += s;
                s = a.w * a.w; asm volatile("" : "+v"(s)); rj[3] += s;
                s = b4.x * b4.x; asm volatile("" : "+v"(s)); rj[4] += s;
                s = b4.y * b4.y; asm volatile("" : "+v"(s)); rj[5] += s;
                s = b4.z * b4.z; asm volatile("" : "+v"(s)); rj[6] += s;
                s = b4.w * b4.w; asm volatile("" : "+v"(s)); rj[7] += s;
            }
            half[h] = ((rj[0] + rj[1]) + (rj[2] + rj[3])) +
                      ((rj[4] + rj[5]) + (rj[6] + rj[7]));
        }
        zn[b * 1024 + hw0 + t] = half[0] + half[1];
    }
}

// ---- kernel 2: bf16 MFMA coarse, 128x128, LDS transpose-reduce epilogue
// (r10/r14 — the occupancy sweet spot; r9/r16 wide tiles both regressed) ----
__global__ __launch_bounds__(256) void k_coarse(
    const ushort* __restrict__ z16, const ushort* __restrict__ e16,
    ushort* __restrict__ tbl) {
    __shared__ char smem[35840];
    char* As = smem;
    char* Bs = smem + 16384;
    float* parts = (float*)smem;
    ushort* tb = (ushort*)(smem + 34816);
    const int tid = threadIdx.x;
    const int w = tid >> 6, lane = tid & 63;
    const int tx = lane & 15, q = lane >> 4;
    const int row0 = blockIdx.x * 128, c0 = blockIdx.y * 128;
    const int Am = (w & 1) * 64, Bn = (w >> 1) * 64;

    f32x4 acc[4][4];
#pragma unroll
    for (int mi = 0; mi < 4; ++mi)
#pragma unroll
        for (int ni = 0; ni < 4; ++ni) acc[mi][ni] = (f32x4){0.f, 0.f, 0.f, 0.f};

    for (int k0 = 0; k0 < K_DIM; k0 += 64) {
#pragma unroll
        for (int j = 0; j < 4; ++j) {
            int r = (w * 4 + j) * 8 + (lane >> 3);
            int c = (lane & 7) ^ (r & 7);
            gl16(z16 + (((size_t)(row0 + r)) << 8) + k0 + (c << 3),
                 As + (w * 4 + j) * 1024);
            gl16(e16 + (((size_t)(c0 + r)) << 8) + k0 + (c << 3),
                 Bs + (w * 4 + j) * 1024);
        }
        __syncthreads();
#pragma unroll
        for (int ks = 0; ks < 2; ++ks) {
            int cd = ks * 4;
            bf16x8 af[4], bfv[4];
#pragma unroll
            for (int mi = 0; mi < 4; ++mi)
                af[mi] = *(const bf16x8*)(As + (Am + mi * 16 + tx) * 128 +
                                          (((cd + q) ^ (tx & 7)) << 4));
#pragma unroll
            for (int ni = 0; ni < 4; ++ni)
                bfv[ni] = *(const bf16x8*)(Bs + (Bn + ni * 16 + tx) * 128 +
                                           (((cd + q) ^ (tx & 7)) << 4));
#pragma unroll
            for (int mi = 0; mi < 4; ++mi)
#pragma unroll
                for (int ni = 0; ni < 4; ++ni)
                    acc[mi][ni] = __builtin_amdgcn_mfma_f32_16x16x32_bf16(
                        af[mi], bfv[ni], acc[mi][ni], 0, 0, 0);
        }
        __syncthreads();
    }

#pragma unroll
    for (int g = 0; g < 2; ++g) {
        int gb = (w >> 1) * 2 + g;
#pragma unroll
        for (int mi = 0; mi < 4; ++mi) {
#pragma unroll
            for (int e = 0; e < 4; ++e) {
                float pm = fmaxf(acc[mi][2 * g][e], acc[mi][2 * g + 1][e]);
                int row = Am + mi * 16 + q * 4 + e;
                parts[(gb * 128 + row) * 17 + tx] = pm;
            }
        }
    }
    __syncthreads();
#pragma unroll
    for (int r2 = 0; r2 < 2; ++r2) {
        int p = tid * 2 + r2;
        const float* pr = parts + p * 17;
        float f0 = fmaxf(pr[0], pr[1]), f1 = fmaxf(pr[2], pr[3]);
        float f2 = fmaxf(pr[4], pr[5]), f3 = fmaxf(pr[6], pr[7]);
        float f4 = fmaxf(pr[8], pr[9]), f5 = fmaxf(pr[10], pr[11]);
        float f6 = fmaxf(pr[12], pr[13]), f7 = fmaxf(pr[14], pr[15]);
        float m = fmaxf(fmaxf(fmaxf(f0, f1), fmaxf(f2, f3)),
                        fmaxf(fmaxf(f4, f5), fmaxf(f6, f7)));
        tb[(p & 127) * 4 + (p >> 7)] = __half_as_ushort(__float2half(m));
    }
    __syncthreads();
    if (tid < 128) {
        ushort4 v = *(ushort4*)(tb + tid * 4);
        *(ushort4*)(tbl + (size_t)(row0 + tid) * 256 + blockIdx.y * 4) = v;
    }
}

// ---- kernel 3: flag pass (r14) ----
__global__ void k_flag(const ushort* __restrict__ tbl, ushort* __restrict__ bucket,
                       unsigned* __restrict__ gcnt,
                       unsigned long long* __restrict__ best) {
    const int wid = threadIdx.x >> 6, lane = threadIdx.x & 63;
    const int n = blockIdx.x * 4 + wid;
    if (lane == 0) best[n] = 0xFFFFFFFFFFFFFFFFull;
    ushort4 raw = *(const ushort4*)(tbl + (size_t)n * 256 + lane * 4);
    float gm[4];
    gm[0] = __half2float(__ushort_as_half(raw.x));
    gm[1] = __half2float(__ushort_as_half(raw.y));
    gm[2] = __half2float(__ushort_as_half(raw.z));
    gm[3] = __half2float(__ushort_as_half(raw.w));
    float gmax = fmaxf(fmaxf(gm[0], gm[1]), fmaxf(gm[2], gm[3]));
#pragma unroll
    for (int m = 1; m < 64; m <<= 1) gmax = fmaxf(gmax, __shfl_xor(gmax, m, 64));
    const float th = gmax - 1.0e-4f;
#pragma unroll
    for (int i = 0; i < 4; ++i) {
        if (gm[i] >= th) {
            int g = lane * 4 + i;
            unsigned pos = atomicAdd(&gcnt[g], 1u);
            bucket[(size_t)g * NROWS + pos] = (ushort)n;
        }
    }
}

// ---- kernel 4: exact rescore; 4 blocks per group, early-exit (r14) ----
__global__ __launch_bounds__(256) void k_rescore2(
    const float* __restrict__ zf32, const float* __restrict__ emb,
    const float* __restrict__ zn, const ushort* __restrict__ bucket,
    const unsigned* __restrict__ gcnt, unsigned long long* __restrict__ best) {
    __shared__ float eg[32 * 257];
    __shared__ float zs[8][256];
    __shared__ ushort rid[8];
    __shared__ float arow[8];
    const int g = blockIdx.x >> 2;
    const int split = blockIdx.x & 3;
    const int t = threadIdx.x;
    const int cnt = (int)gcnt[g];
    if (split * 8 >= cnt) return;
#pragma unroll
    for (int i = 0; i < 8; ++i) {
        int f = t + i * 256;
        int c = f >> 6, k4 = f & 63;
        float4 v = *(const float4*)(emb + (size_t)(g * 32 + c) * 256 + k4 * 4);
        float* dst = eg + c * 257 + k4 * 4;
        dst[0] = v.x; dst[1] = v.y; dst[2] = v.z; dst[3] = v.w;
    }
    for (int base = split * 8; base < cnt; base += 32) {
        __syncthreads();
        if (t < 8) {
            int i = base + t;
            if (i < cnt) {
                ushort r = bucket[(size_t)g * NROWS + i];
                rid[t] = r;
                arow[t] = zn[r];
            } else {
                rid[t] = 0xFFFF;
            }
        }
        __syncthreads();
#pragma unroll
        for (int i = 0; i < 2; ++i) {
            int f = t + i * 256;
            int s = f >> 6, k4 = f & 63;
            if (rid[s] != 0xFFFF)
                *(float4*)(&zs[s][k4 * 4]) =
                    *(const float4*)(zf32 + (size_t)rid[s] * 256 + k4 * 4);
        }
        __syncthreads();
        const int lane = t & 63, w = t >> 6;
        const int slot = w * 2 + (lane >> 5);
        const int code = lane & 31;
        if (rid[slot] != 0xFFFF) {
            const float* zr = zs[slot];
            const float* er = eg + code * 257;
            float acc = 0.f;
#pragma unroll 8
            for (int k = 0; k < 256; ++k) acc = fmaf(zr[k], er[k], acc);
            float d = arow[slot] - 2.f * acc;
            unsigned fb = __float_as_uint(d);
            fb ^= (fb & 0x80000000u) ? 0xFFFFFFFFu : 0x80000000u;
            unsigned long long pk =
                ((unsigned long long)fb << 32) | (unsigned)(g * 32 + code);
#pragma unroll
            for (int m = 1; m < 32; m <<= 1) {
                unsigned long long o = __shfl_xor(pk, m, 64);
                if (o < pk) pk = o;
            }
            if ((lane & 31) == 0) atomicMin(&best[rid[slot]], pk);
        }
    }
}

// ---- kernel 5: gather z_q + loss + oidx; 64 rows/block (r11 — best measured) ----
__global__ __launch_bounds__(256) void k_gather(
    const float* __restrict__ z, const float* __restrict__ emb,
    const unsigned long long* __restrict__ best, float* __restrict__ zq,
    float* __restrict__ oidx, float* __restrict__ loss) {
    __shared__ float eg[64][257];
    __shared__ float lsum[4];
    const int t = threadIdx.x;
    const int n0 = blockIdx.x * 64;
    const int b = n0 >> 10, hw0 = n0 & 1023;
    {
        const int row = t >> 2;
        const int cbase = (t & 3) * 64;
        const int code = (int)(unsigned)(best[n0 + row] & 0xFFFFFFFFull);
        if ((t & 3) == 0) oidx[n0 + row] = (float)code;
        const float* er = emb + (size_t)code * 256 + cbase;
        float* dst = &eg[row][cbase];
#pragma unroll
        for (int i = 0; i < 16; ++i) {
            float4 v = *(const float4*)(er + i * 4);
            dst[i * 4 + 0] = v.x; dst[i * 4 + 1] = v.y;
            dst[i * 4 + 2] = v.z; dst[i * 4 + 3] = v.w;
        }
    }
    __syncthreads();
    const int w = t >> 6, lane = t & 63;
    float acc = 0.f;
    const size_t obase = (size_t)b * 262144 + hw0 + lane;
#pragma unroll 4
    for (int ci = 0; ci < 64; ++ci) {
        int c = w * 64 + ci;
        float e = eg[lane][c];
        size_t off = obase + (size_t)c * 1024;
        float zv = z[off];
        zq[off] = e;
        float d = e - zv;
        acc = fmaf(d, d, acc);
    }
#pragma unroll
    for (int m = 32; m; m >>= 1) acc += __shfl_xor(acc, m, 64);
    if (lane == 0) lsum[w] = acc;
    __syncthreads();
    if (t == 0) {
        float s = (lsum[0] + lsum[1]) + (lsum[2] + lsum[3]);
        atomicAdd(loss, s * (2.f / 4194304.f));
    }
}

extern "C" void kernel_launch(void* const* d_in, const int* in_sizes, int n_in,
                              void* d_out, int out_size, void* d_ws, size_t ws_size,
                              hipStream_t stream) {
    const float* z = (const float*)d_in[0];
    const float* emb = (const float*)d_in[1];
    float* out = (float*)d_out;
    float* zq = out;
    float* loss = out + 4194304;
    float* oidx = out + 4194305;
    float* zf32 = out;

    ushort* z16 = (ushort*)d_ws;               // 8 MB; dead after k_coarse
    ushort* e16 = z16 + 4194304;               // 4 MB
    ushort* tbl = e16 + 2097152;               // 8 MB [n][256] f16
    float* zn = (float*)(tbl + 4194304);       // 64 KB
    unsigned long long* best = (unsigned long long*)(zn + 16384);  // 128 KB
    unsigned* gcnt = (unsigned*)(best + 16384);                    // 1 KB
    ushort* bucket = z16;                      // alias dead z16

    k_cvt<<<dim3(768), dim3(256), 0, stream>>>(z, zf32, z16, zn, emb, e16, gcnt, loss);
    k_coarse<<<dim3(NROWS / 128, NCODES / 128), dim3(256), 0, stream>>>(z16, e16, tbl);
    k_flag<<<dim3(NROWS / 4), dim3(256), 0, stream>>>(tbl, bucket, gcnt, best);
    k_rescore2<<<dim3(1024), dim3(256), 0, stream>>>(zf32, emb, zn, bucket, gcnt, best);
    k_gather<<<dim3(NROWS / 64), dim3(256), 0, stream>>>(z, emb, best, zq, oidx, loss);
}